// Round 4
// baseline (640.465 us; speedup 1.0000x reference)
//
#include <hip/hip_runtime.h>
#include <stdint.h>

// B=4, T=2048, E=1024, H=16, HS=64.  M = 8192 token rows. All I/O fp32;
// matmuls run bf16-input / fp32-accumulate on MFMA (16x16x32_bf16).

typedef __attribute__((ext_vector_type(8))) short s16x8;   // 8 bf16 (4 VGPR)
typedef __attribute__((ext_vector_type(4))) float f32x4;   // MFMA acc
typedef unsigned short u16;
typedef __attribute__((ext_vector_type(4))) unsigned short u16x4;

// XOR swizzle: spreads row r's 16B blocks across banks.
#define XSW(r) ((((r) & 7) ^ (((r) >> 3) & 7)) << 4)

__device__ __forceinline__ u16 f2bf(float f) {   // RNE fp32 -> bf16
    uint32_t u = __float_as_uint(f);
    u += 0x7fffu + ((u >> 16) & 1u);
    return (u16)(u >> 16);
}
__device__ __forceinline__ float bf2f(u16 u) {
    return __uint_as_float(((uint32_t)u) << 16);
}
__device__ __forceinline__ uint32_t pk2(float a, float b) {
    return (uint32_t)f2bf(a) | ((uint32_t)f2bf(b) << 16);
}
__device__ __forceinline__ float exp2_fast(float x) {   // D = 2^x
    float r;
    asm("v_exp_f32 %0, %1" : "=v"(r) : "v"(x));
    return r;
}

// async global(16B/lane) -> LDS (wave-uniform base + lane*16)
__device__ __forceinline__ void gld16(const void* g, void* l) {
    __builtin_amdgcn_global_load_lds(
        (const __attribute__((address_space(1))) unsigned int*)g,
        (__attribute__((address_space(3))) unsigned int*)l, 16, 0, 0);
}

// ---------------------------------------------------------------------------
// LayerNorm fp32 -> bf16. One block per 1024-float row.
// ---------------------------------------------------------------------------
__global__ __launch_bounds__(256)
void ln_bf16(const float* __restrict__ x, const float* __restrict__ g,
             const float* __restrict__ bta, u16* __restrict__ y) {
    __shared__ float red[8];
    const int row = blockIdx.x;
    const int t = threadIdx.x;
    const float4 xv = ((const float4*)(x + (size_t)row * 1024))[t];
    float s = xv.x + xv.y + xv.z + xv.w;
    float q = xv.x*xv.x + xv.y*xv.y + xv.z*xv.z + xv.w*xv.w;
#pragma unroll
    for (int off = 32; off; off >>= 1) {
        s += __shfl_down(s, off, 64);
        q += __shfl_down(q, off, 64);
    }
    if ((t & 63) == 0) { red[(t>>6)*2] = s; red[(t>>6)*2+1] = q; }
    __syncthreads();
    const float st = red[0]+red[2]+red[4]+red[6];
    const float qt = red[1]+red[3]+red[5]+red[7];
    const float mu = st * (1.f/1024.f);
    const float rs = rsqrtf(qt*(1.f/1024.f) - mu*mu + 1e-5f);
    const float4 gv = ((const float4*)g)[t];
    const float4 bv = ((const float4*)bta)[t];
    u16x4 o;
    o.x = f2bf((xv.x-mu)*rs*gv.x + bv.x);
    o.y = f2bf((xv.y-mu)*rs*gv.y + bv.y);
    o.z = f2bf((xv.z-mu)*rs*gv.z + bv.z);
    o.w = f2bf((xv.w-mu)*rs*gv.w + bv.w);
    ((u16x4*)(y + (size_t)row*1024))[t] = o;
}

// ---------------------------------------------------------------------------
// Generic transpose: out[n][k] = bf16(in[k][n]); in is [K][N] fp32.
// ---------------------------------------------------------------------------
__global__ __launch_bounds__(256)
void transpose_f32_bf16(const float* __restrict__ in, u16* __restrict__ out,
                        int K, int N) {
    __shared__ float tile[64][65];
    const int k0 = blockIdx.x * 64;
    const int n0 = blockIdx.y * 64;
    const int t = threadIdx.x;
    const int r = t >> 2;
    const int c = (t & 3) * 16;
    const float* ip = in + (size_t)(k0 + r) * N + n0 + c;
#pragma unroll
    for (int i = 0; i < 4; ++i) {
        const float4 v = *(const float4*)(ip + i*4);
        tile[r][c+i*4+0]=v.x; tile[r][c+i*4+1]=v.y;
        tile[r][c+i*4+2]=v.z; tile[r][c+i*4+3]=v.w;
    }
    __syncthreads();
    u16 tmp[16] __attribute__((aligned(16)));
#pragma unroll
    for (int i = 0; i < 16; ++i) tmp[i] = f2bf(tile[c+i][r]);
    u16* op = out + (size_t)(n0 + r) * K + k0 + c;
    *(s16x8*)op       = *(const s16x8*)&tmp[0];
    *(s16x8*)(op + 8) = *(const s16x8*)&tmp[8];
}

// ---------------------------------------------------------------------------
// Pack Wq/Wk/Wv [H=16][E=1024][HS=64] -> WcatT [3072 n][1024 k] bf16.
// ---------------------------------------------------------------------------
__global__ __launch_bounds__(256)
void pack_wcat(const float* __restrict__ Wq, const float* __restrict__ Wk,
               const float* __restrict__ Wv, u16* __restrict__ out) {
    __shared__ float tile[64][65];
    const int ph = blockIdx.y;
    const int p = ph >> 4, h = ph & 15;
    const float* W = (p == 0) ? Wq : (p == 1 ? Wk : Wv);
    const float* in = W + (size_t)h * 64 * 1024;     // [1024 k][64 d]
    const int k0 = blockIdx.x * 64;
    const int t = threadIdx.x;
    const int r = t >> 2;
    const int c = (t & 3) * 16;
    const float* ip = in + (size_t)(k0 + r) * 64 + c;
#pragma unroll
    for (int i = 0; i < 4; ++i) {
        const float4 v = *(const float4*)(ip + i*4);
        tile[r][c+i*4+0]=v.x; tile[r][c+i*4+1]=v.y;
        tile[r][c+i*4+2]=v.z; tile[r][c+i*4+3]=v.w;
    }
    __syncthreads();
    u16 tmp[16] __attribute__((aligned(16)));
#pragma unroll
    for (int i = 0; i < 16; ++i) tmp[i] = f2bf(tile[c+i][r]);
    u16* op = out + (size_t)(p*1024 + h*64 + r) * 1024 + k0 + c;
    *(s16x8*)op       = *(const s16x8*)&tmp[0];
    *(s16x8*)(op + 8) = *(const s16x8*)&tmp[8];
}

// ---------------------------------------------------------------------------
// bf16 MFMA GEMM, m97 structure: 128x128 tile, BK=64, 4 waves, linear LDS,
// global_load_lds(16B) staging, 2-barrier K-loop.
// SPLIT_V (qkv GEMM): cols >= 2048 (V projection) are written TRANSPOSED to
// vT[(b*16+h)*64 + d][2048 t] so attention can stage V^T with b128 ops.
// ---------------------------------------------------------------------------
template<bool RELU, bool HAS_BIAS, bool HAS_RES, bool OUT_BF16, bool SPLIT_V>
__global__ __launch_bounds__(256)
void bgemm(const u16* __restrict__ A, int lda,
           const u16* __restrict__ Bt, int ldb,
           void* Cv, int ldc,
           const float* __restrict__ bias,
           const float* Res, int ldres, int K,
           u16* __restrict__ vT)
{
    __shared__ u16 Als[128*64];
    __shared__ u16 Bls[128*64];
    const int tid = threadIdx.x;
    const int wid = tid >> 6, lane = tid & 63;
    const int bm = blockIdx.y * 128, bn = blockIdx.x * 128;
    const int wr = (wid >> 1) * 64, wc = (wid & 1) * 64;
    const int fr = lane & 15, fq = lane >> 4;
    const int sr8 = lane >> 3, sc8 = (lane & 7) * 8;

    const f32x4 zero = {0.f, 0.f, 0.f, 0.f};
    f32x4 acc[4][4];
#pragma unroll
    for (int m = 0; m < 4; ++m)
#pragma unroll
        for (int n = 0; n < 4; ++n) acc[m][n] = zero;

    const u16* Ap = A  + (size_t)(bm + wid*32 + sr8) * lda + sc8;
    const u16* Bp = Bt + (size_t)(bn + wid*32 + sr8) * ldb + sc8;
    u16* Alp = Als + wid*2048 + lane*8;
    u16* Blp = Bls + wid*2048 + lane*8;

    for (int k0 = 0; k0 < K; k0 += 64) {
#pragma unroll
        for (int c = 0; c < 4; ++c) {
            gld16(Ap + (size_t)(c*8)*lda + k0, Alp + c*512);
            gld16(Bp + (size_t)(c*8)*ldb + k0, Blp + c*512);
        }
        __syncthreads();   // drains vmcnt: tile resident
#pragma unroll
        for (int kk = 0; kk < 2; ++kk) {
            s16x8 af[4], bf[4];
#pragma unroll
            for (int m = 0; m < 4; ++m)
                af[m] = *(const s16x8*)((const char*)Als + (wr+m*16+fr)*128 + kk*64 + fq*16);
#pragma unroll
            for (int n = 0; n < 4; ++n)
                bf[n] = *(const s16x8*)((const char*)Bls + (wc+n*16+fr)*128 + kk*64 + fq*16);
#pragma unroll
            for (int m = 0; m < 4; ++m)
#pragma unroll
                for (int n = 0; n < 4; ++n)
                    acc[m][n] = __builtin_amdgcn_mfma_f32_16x16x32_bf16(
                        af[m], bf[n], acc[m][n], 0, 0, 0);
        }
        __syncthreads();   // reads done before next overwrite
    }

    // epilogue: C/D frag mapping col = lane&15, row = (lane>>4)*4 + j
    float* Cf = (float*)Cv;
    u16*  Cb = (u16*)Cv;
    if (SPLIT_V && bn >= 2048) {
        // V projection -> vT[(b*16+h)*64 + d][t]
#pragma unroll
        for (int n = 0; n < 4; ++n) {
            const int local = bn + wc + n*16 + fr - 2048;
            const int hh = local >> 6, dd = local & 63;
#pragma unroll
            for (int m = 0; m < 4; ++m) {
#pragma unroll
                for (int j = 0; j < 4; ++j) {
                    const int row = bm + wr + m*16 + fq*4 + j;
                    const int bb = row >> 11, tt = row & 2047;
                    vT[((size_t)(bb*16 + hh)*64 + dd)*2048 + tt] = f2bf(acc[m][n][j]);
                }
            }
        }
        return;
    }
#pragma unroll
    for (int n = 0; n < 4; ++n) {
        const int col = bn + wc + n*16 + fr;
        const float bval = HAS_BIAS ? bias[col] : 0.f;
#pragma unroll
        for (int m = 0; m < 4; ++m) {
#pragma unroll
            for (int j = 0; j < 4; ++j) {
                const int row = bm + wr + m*16 + fq*4 + j;
                float v = acc[m][n][j] + bval;
                if (HAS_RES) v += Res[(size_t)row * ldres + col];
                if (RELU)    v = fmaxf(v, 0.f);
                if (OUT_BF16) Cb[(size_t)row * ldc + col] = f2bf(v);
                else          Cf[(size_t)row * ldc + col] = v;
            }
        }
    }
}

// ---------------------------------------------------------------------------
// Flash attention, swapped-QK^T bf16 MFMA, exp2-domain softmax.
// qk: [token][2048] = {q(1024), k(1024)} bf16.  vT: [(b*16+h)*64+d][2048 t].
// Block = 64 q-rows of one (b,h); 4 waves; lane owns q-row = fr.
// KVBLK=128; V^T staged with b128 (no scalar transpose).  out: [tok][h*64+d].
// ---------------------------------------------------------------------------
__global__ __launch_bounds__(256)
void attn_bf16(const u16* __restrict__ qk, const u16* __restrict__ vT,
               u16* __restrict__ out) {
    __shared__ u16 Ks[128*64];      // [key][d]   stride 128B, XSW(key)
    __shared__ u16 Vt[64*128];      // [d][key]   stride 256B, XSW(d)
    __shared__ u16 Ps[4][16*128];   // per-wave [q16][key128] stride 256B, XSW(q)
    const int b = blockIdx.y >> 4, h = blockIdx.y & 15;
    const int q0 = blockIdx.x << 6;
    const int tid = threadIdx.x;
    const int wid = tid >> 6, lane = tid & 63;
    const int fr = lane & 15, fq = lane >> 4;
    const int srow = tid >> 2;           // 0..63
    const int sce  = (tid & 3) * 16;     // u16 col group (K/Q staging)
    const int vd   = tid >> 4;           // 0..15 (V^T staging d base)
    const int vt0  = (tid & 15) * 8;     // V^T staging t chunk
    const size_t tokbase = (size_t)b * 2048;
    const u16* vbase = vT + (size_t)(b*16 + h) * 64 * 2048;
    const f32x4 zero = {0.f, 0.f, 0.f, 0.f};

    // ---- stage Q into Ps space (transient), build pre-scaled Q frags ----
    u16* Qst = (u16*)Ps;                 // [64 q][64 d], stride 128B, XSW(q)
    {
        const u16* qp = qk + (tokbase + q0 + srow)*2048 + h*64 + sce;
        const s16x8 v0 = *(const s16x8*)qp;
        const s16x8 v1 = *(const s16x8*)(qp + 8);
        *(s16x8*)((char*)Qst + srow*128 + ((sce*2)      ^ XSW(srow))) = v0;
        *(s16x8*)((char*)Qst + srow*128 + ((sce*2 + 16) ^ XSW(srow))) = v1;
    }
    __syncthreads();
    s16x8 qf[2];     // Q[q=fr][d=kk*32+fq*8+i] scaled by 0.125*log2(e)
    {
        const int qrow = wid*16 + fr;
        const float qscale = 0.125f * 1.44269504f;
#pragma unroll
        for (int kk = 0; kk < 2; ++kk) {
            const s16x8 raw = *(const s16x8*)((const char*)Qst + qrow*128
                                 + ((kk*64 + fq*16) ^ XSW(qrow)));
#pragma unroll
            for (int i = 0; i < 8; ++i)
                qf[kk][i] = (short)f2bf(bf2f((u16)raw[i]) * qscale);
        }
    }

    float m_run = -1e30f, l_run = 0.f;   // log2 domain
    f32x4 oacc[4];   // O^T frag nd: col q=fr, row d = nd*16+fq*4+j
#pragma unroll
    for (int nd = 0; nd < 4; ++nd) oacc[nd] = zero;

    // prologue: load tile kt=0 into regs
    s16x8 kr[4], vr[4];
    {
        const u16* kp0 = qk + (tokbase + srow)*2048 + 1024 + h*64 + sce;
        kr[0] = *(const s16x8*)kp0;
        kr[1] = *(const s16x8*)(kp0 + 8);
        kr[2] = *(const s16x8*)(kp0 + (size_t)64*2048);
        kr[3] = *(const s16x8*)(kp0 + (size_t)64*2048 + 8);
#pragma unroll
        for (int c = 0; c < 4; ++c)
            vr[c] = *(const s16x8*)(vbase + (size_t)(vd + 16*c)*2048 + vt0);
    }

    for (int kt = 0; kt < 2048; kt += 128) {
        __syncthreads();                 // (A) prev-tile LDS reads done
        {   // K staging (b128, swizzled)
            const int r0 = srow, r1 = srow + 64;
            *(s16x8*)((char*)Ks + r0*128 + ((sce*2)      ^ XSW(r0))) = kr[0];
            *(s16x8*)((char*)Ks + r0*128 + ((sce*2 + 16) ^ XSW(r0))) = kr[1];
            *(s16x8*)((char*)Ks + r1*128 + ((sce*2)      ^ XSW(r1))) = kr[2];
            *(s16x8*)((char*)Ks + r1*128 + ((sce*2 + 16) ^ XSW(r1))) = kr[3];
        }
#pragma unroll
        for (int c = 0; c < 4; ++c) {    // V^T staging (b128, swizzled)
            const int d = vd + 16*c;
            *(s16x8*)((char*)Vt + d*256 + ((vt0*2) ^ XSW(d))) = vr[c];
        }
        __syncthreads();                 // (B) tile resident

        // T14: issue next tile's global loads now (hidden under compute)
        if (kt + 128 < 2048) {
            const u16* kp0 = qk + (tokbase + kt + 128 + srow)*2048 + 1024 + h*64 + sce;
            kr[0] = *(const s16x8*)kp0;
            kr[1] = *(const s16x8*)(kp0 + 8);
            kr[2] = *(const s16x8*)(kp0 + (size_t)64*2048);
            kr[3] = *(const s16x8*)(kp0 + (size_t)64*2048 + 8);
#pragma unroll
            for (int c = 0; c < 4; ++c)
                vr[c] = *(const s16x8*)(vbase + (size_t)(vd + 16*c)*2048
                                        + kt + 128 + vt0);
        }

        // ---- S^T = mfma(K, Q): lane gets scores for q=fr, keys n*16+fq*4+j
        f32x4 sv[8];
        __builtin_amdgcn_s_setprio(1);
#pragma unroll
        for (int n = 0; n < 8; ++n) {
            sv[n] = zero;
            const int r = n*16 + fr;
#pragma unroll
            for (int kk = 0; kk < 2; ++kk) {
                const s16x8 kf = *(const s16x8*)((const char*)Ks + r*128
                                     + ((kk*64 + fq*16) ^ XSW(r)));
                sv[n] = __builtin_amdgcn_mfma_f32_16x16x32_bf16(kf, qf[kk], sv[n], 0,0,0);
            }
        }
        __builtin_amdgcn_s_setprio(0);

        // ---- online softmax (log2 domain): 32 in-reg values + 2 shfl_xor
        float pv[32];
        float mx = -1e30f;
#pragma unroll
        for (int n = 0; n < 8; ++n)
#pragma unroll
            for (int j = 0; j < 4; ++j) {
                const float s = sv[n][j];
                pv[n*4 + j] = s;
                mx = fmaxf(mx, s);
            }
        mx = fmaxf(mx, __shfl_xor(mx, 16, 64));
        mx = fmaxf(mx, __shfl_xor(mx, 32, 64));
        const float mn = fmaxf(m_run, mx);
        const float al = exp2_fast(m_run - mn);
        m_run = mn;
        float rs = 0.f;
#pragma unroll
        for (int t = 0; t < 32; ++t) { pv[t] = exp2_fast(pv[t] - mn); rs += pv[t]; }
        rs += __shfl_xor(rs, 16, 64);
        rs += __shfl_xor(rs, 32, 64);
        l_run = l_run * al + rs;
#pragma unroll
        for (int nd = 0; nd < 4; ++nd)
#pragma unroll
            for (int j = 0; j < 4; ++j) oacc[nd][j] *= al;

        // ---- P to wave-local LDS (packed b64, swizzled); no block barrier
        u16* Pw = (u16*)Ps + wid*2048;
#pragma unroll
        for (int n = 0; n < 8; ++n) {
            const uint64_t w = (uint64_t)pk2(pv[n*4+0], pv[n*4+1])
                             | ((uint64_t)pk2(pv[n*4+2], pv[n*4+3]) << 32);
            *(uint64_t*)((char*)Pw + fr*256 + ((n*32 + fq*8) ^ XSW(fr))) = w;
        }
        asm volatile("s_waitcnt lgkmcnt(0)" ::: "memory");
        __builtin_amdgcn_sched_barrier(0);

        // ---- O^T += mfma(V^T, P^T)
        s16x8 pf[4];
#pragma unroll
        for (int k2 = 0; k2 < 4; ++k2)
            pf[k2] = *(const s16x8*)((const char*)Pw + fr*256
                         + ((k2*64 + fq*16) ^ XSW(fr)));
        __builtin_amdgcn_s_setprio(1);
#pragma unroll
        for (int nd = 0; nd < 4; ++nd) {
            const int d = nd*16 + fr;
#pragma unroll
            for (int k2 = 0; k2 < 4; ++k2) {
                const s16x8 vf = *(const s16x8*)((const char*)Vt + d*256
                                     + ((k2*64 + fq*16) ^ XSW(d)));
                oacc[nd] = __builtin_amdgcn_mfma_f32_16x16x32_bf16(vf, pf[k2], oacc[nd], 0,0,0);
            }
        }
        __builtin_amdgcn_s_setprio(0);
    }

    // ---- epilogue: lane holds O[q=fr][d = nd*16+fq*4+j]
    const float inv = 1.0f / l_run;
    const size_t row = tokbase + q0 + wid*16 + fr;
#pragma unroll
    for (int nd = 0; nd < 4; ++nd) {
        u16x4 o;
#pragma unroll
        for (int j = 0; j < 4; ++j) o[j] = f2bf(oacc[nd][j] * inv);
        *(u16x4*)(out + row*1024 + h*64 + nd*16 + fq*4) = o;
    }
}

// ---------------------------------------------------------------------------
extern "C" void kernel_launch(void* const* d_in, const int* in_sizes, int n_in,
                              void* d_out, int out_size, void* d_ws, size_t ws_size,
                              hipStream_t stream) {
    (void)in_sizes; (void)n_in; (void)out_size; (void)ws_size;
    const float* x     = (const float*)d_in[0];
    const float* ln1_g = (const float*)d_in[1];
    const float* ln1_b = (const float*)d_in[2];
    const float* Wq    = (const float*)d_in[3];
    const float* Wk    = (const float*)d_in[4];
    const float* Wv    = (const float*)d_in[5];
    const float* Wo    = (const float*)d_in[6];
    const float* bo    = (const float*)d_in[7];
    const float* ln2_g = (const float*)d_in[8];
    const float* ln2_b = (const float*)d_in[9];
    const float* W1    = (const float*)d_in[10];
    const float* b1    = (const float*)d_in[11];
    const float* W2    = (const float*)d_in[12];
    const float* b2    = (const float*)d_in[13];
    float* out = (float*)d_out;

    char* w = (char*)d_ws;
    u16* WcatT = (u16*)w;  w += (size_t)3072*1024*2;   // [3072 n][1024 k]
    u16* WoT   = (u16*)w;  w += (size_t)1024*1024*2;   // [1024 n][1024 k]
    u16* W1T   = (u16*)w;  w += (size_t)4096*1024*2;   // [4096 n][1024 k]
    u16* W2T   = (u16*)w;  w += (size_t)1024*4096*2;   // [1024 n][4096 k]
    u16* hb    = (u16*)w;  w += (size_t)8192*1024*2;   // LN out (reused)
    u16* qkb   = (u16*)w;  w += (size_t)8192*2048*2;   // q,k projections
    u16* vTb   = (u16*)w;  w += (size_t)64*64*2048*2;  // V^T [(b,h)*64+d][t]
    u16* attno = (u16*)w;  w += (size_t)8192*1024*2;   // attention out
    u16* a1    = (u16*)w;  w += (size_t)8192*4096*2;   // FFN hidden

    // weight packs (bf16, transposed to [N][K])
    pack_wcat<<<dim3(16, 48), 256, 0, stream>>>(Wq, Wk, Wv, WcatT);
    transpose_f32_bf16<<<dim3(16, 16), 256, 0, stream>>>(Wo, WoT, 1024, 1024);
    transpose_f32_bf16<<<dim3(16, 64), 256, 0, stream>>>(W1, W1T, 1024, 4096);
    transpose_f32_bf16<<<dim3(64, 16), 256, 0, stream>>>(W2, W2T, 4096, 1024);

    // h = LN1(x)
    ln_bf16<<<dim3(8192), 256, 0, stream>>>(x, ln1_g, ln1_b, hb);
    // qkv = h @ Wcat   (q,k -> qkb [tok][2048]; v -> vTb transposed)
    bgemm<false,false,false,true,true><<<dim3(24, 64), 256, 0, stream>>>(
        hb, 1024, WcatT, 1024, qkb, 2048, nullptr, nullptr, 0, 1024, vTb);
    // attention
    attn_bf16<<<dim3(32, 64), 256, 0, stream>>>(qkb, vTb, attno);
    // x2 = x + o @ Wo + bo   (fp32 out)
    bgemm<false,true,true,false,false><<<dim3(8, 64), 256, 0, stream>>>(
        attno, 1024, WoT, 1024, out, 1024, bo, x, 1024, 1024, nullptr);
    // h2 = LN2(x2)
    ln_bf16<<<dim3(8192), 256, 0, stream>>>(out, ln2_g, ln2_b, hb);
    // a1 = relu(h2 @ W1 + b1)  (bf16 out)
    bgemm<true,true,false,true,false><<<dim3(32, 64), 256, 0, stream>>>(
        hb, 1024, W1T, 1024, a1, 4096, b1, nullptr, 0, 1024, nullptr);
    // out = x2 + a1 @ W2 + b2  (fp32, in-place residual)
    bgemm<false,true,true,false,false><<<dim3(8, 64), 256, 0, stream>>>(
        a1, 4096, W2T, 4096, out, 1024, b2, out, 1024, 4096, nullptr);
}